// Round 13
// baseline (133.336 us; speedup 1.0000x reference)
//
#include <hip/hip_runtime.h>
#include <hip/hip_bf16.h>

using u16 = unsigned short;
typedef __bf16 bf16x8 __attribute__((ext_vector_type(8)));
typedef float f32x4 __attribute__((ext_vector_type(4)));

#define N_B   16
#define L_S   512
#define D_F   256
#define T_MEL 4096
#define M_TOT (N_B * L_S)
#define OUT_ELEMS ((size_t)N_B * T_MEL * D_F)   // fp32 elems
#define H1_ELEMS  ((size_t)M_TOT * D_F)         // bf16 elems
#define WP_ELEMS  (24 * 8192)                   // packed weight elems per conv
#define TBLK 128

__device__ __forceinline__ u16 f2bf(float f) {
  __hip_bfloat16 h = __float2bfloat16(f);
  return *(u16*)&h;
}

__device__ __forceinline__ bf16x8 pack8(float4 v0, float4 v1) {
  union { bf16x8 h; u16 u[8]; } r;
  r.u[0] = f2bf(v0.x); r.u[1] = f2bf(v0.y); r.u[2] = f2bf(v0.z); r.u[3] = f2bf(v0.w);
  r.u[4] = f2bf(v1.x); r.u[5] = f2bf(v1.y); r.u[6] = f2bf(v1.z); r.u[7] = f2bf(v1.w);
  return r.h;
}

// ---------------------------------------------------------------------------
// Weight pack: wp[s][f][ki] = w[f][(s&7)*32+ki][s>>3]  (proven indexing).
// ---------------------------------------------------------------------------
__global__ __launch_bounds__(256)
void pack_kernel(const float* __restrict__ w1, const float* __restrict__ w2,
                 u16* __restrict__ wp1, u16* __restrict__ wp2) {
  int o   = (int)blockIdx.x * 256 + (int)threadIdx.x;   // 0..196607
  int s   = o >> 13;
  int rem = o & 8191;
  int f   = rem >> 5;
  int ki  = rem & 31;
  int d   = ((s & 7) << 5) + ki;
  int tap = s >> 3;
  int src = f * 768 + d * 3 + tap;
  wp1[o] = f2bf(w1[src]);
  wp2[o] = f2bf(w2[src]);
}

// ---------------------------------------------------------------------------
// DIRECT-B conv body (round 13): A staged once in LDS (proven, 1 barrier);
// B-frags loaded straight from global per wave, depth-3 NAMED buffers
// (bA/bB/bC, by-3 loop, compile-time indices; no outer pragma unroll - R9),
// ZERO barriers in the K-loop. Reuse: at 256 blocks (1/CU) the rh=0/rh=1
// waves read identical B fragments -> L1 (32KB; 16KB/step working set)
// absorbs the duplicate, so per-CU L2 line traffic matches R5's staged
// version WITHOUT the lockstep. R12 showed per-step cost scales with work
// through the staging machinery; this removes the machinery.
// Epilogue byte-identical to R8 (same MFMA order -> absmax must hold).
// ---------------------------------------------------------------------------
template<int STAGE>
__device__ __forceinline__ void conv_body_dir(
    const int blk, const int t,
    const float* __restrict__ Xf, const u16* __restrict__ Xh,
    const u16* __restrict__ Wp,
    const float* __restrict__ cb,  const float* __restrict__ lgm,
    const float* __restrict__ lbt, const float* __restrict__ lw,
    const float* __restrict__ lb,  u16* __restrict__ Hout,
    float* __restrict__ dpo,
    u16* As, float* sBias, float* sG, float* sB, float* sLw,
    float (*redS)[4][16], float (*redQ)[4][16])
{
  if (t < 256) {
    sBias[t] = cb[t];
    sG[t]    = lgm[t];
    sB[t]    = lbt[t];
    if (STAGE == 2) sLw[t] = lw[t];
  }

  const int m0   = blk * 32;
  const int n    = m0 >> 9;
  const int l0   = m0 & 511;
  const int wave = t >> 6, lane = t & 63;
  const int cs   = wave & 3;
  const int rh   = wave >> 2;
  const int wc   = cs * 64;
  const int rh16 = rh * 16;
  const int p    = lane & 15, q = lane >> 4;

  f32x4 acc[4];
  #pragma unroll
  for (int i = 0; i < 4; i++) acc[i] = (f32x4){0.f, 0.f, 0.f, 0.f};

  // ---- stage A once (34 x 256, bf16, stride 264) ----
  for (int c = t; c < 1088; c += 512) {
    int row  = c >> 5;
    int col8 = c & 31;
    int l    = l0 + row - 1;
    uint4 val;
    if ((unsigned)l < 512u) {
      if (STAGE == 1) {
        const float* src = Xf + (((size_t)((n << 9) + l)) << 8) + (col8 << 3);
        float4 v0 = *(const float4*)src;
        float4 v1 = *(const float4*)(src + 4);
        bf16x8 pk = pack8(v0, v1);
        __builtin_memcpy(&val, &pk, 16);
      } else {
        val = *(const uint4*)(Xh + (((size_t)((n << 9) + l)) << 8) + (col8 << 3));
      }
    } else {
      val = make_uint4(0u, 0u, 0u, 0u);
    }
    *(uint4*)(As + row * 264 + (col8 << 3)) = val;
  }
  __syncthreads();                        // the ONLY barrier before epilogue

  // ---- K-loop: direct-global B, depth-3 named buffers, no barriers ----
  const u16* wbase = Wp + ((wc + p) << 5) + (q << 3);
  auto LDB = [&](int s, bf16x8 (&b)[4]) {
    const u16* src = wbase + ((size_t)s << 13);
    #pragma unroll
    for (int ct = 0; ct < 4; ct++)
      b[ct] = *(const bf16x8*)(src + (ct << 9));  // ct*16 cols * 32 elems
  };
  auto MF = [&](int s, bf16x8 (&b)[4]) {
    const int tap = s >> 3, dbase = (s & 7) << 5;
    bf16x8 af = *(const bf16x8*)(As + (rh16 + p + tap) * 264 + dbase + (q << 3));
    #pragma unroll
    for (int ct = 0; ct < 4; ct++)
      acc[ct] = __builtin_amdgcn_mfma_f32_16x16x32_bf16(af, b[ct], acc[ct], 0, 0, 0);
  };

  bf16x8 bA[4], bB[4], bC[4];
  LDB(0, bA);
  LDB(1, bB);
  for (int s3 = 0; s3 < 24; s3 += 3) {    // 8 iterations, indices all static
    LDB(s3 + 2, bC);                      // s3+2 <= 23 always
    MF(s3, bA);
    if (s3 + 3 < 24) LDB(s3 + 3, bA);
    MF(s3 + 1, bB);
    if (s3 + 4 < 24) LDB(s3 + 4, bB);
    MF(s3 + 2, bC);
    if (s3 + 5 < 24) LDB(s3 + 5, bC);
  }

  // ---- epilogue: R8 VERBATIM ----
  float s0[4] = {0,0,0,0}, s1[4] = {0,0,0,0};
  #pragma unroll
  for (int ct = 0; ct < 4; ct++) {
    float bias = sBias[wc + ct * 16 + p];
    #pragma unroll
    for (int j = 0; j < 4; j++) {
      float v = acc[ct][j] + bias;
      acc[ct][j] = v;
      s0[j] += v;
      s1[j] += v * v;
    }
  }
  #pragma unroll
  for (int m = 1; m <= 8; m <<= 1) {
    #pragma unroll
    for (int j = 0; j < 4; j++) {
      s0[j] += __shfl_xor(s0[j], m);
      s1[j] += __shfl_xor(s1[j], m);
    }
  }
  if (p == 0) {
    #pragma unroll
    for (int j = 0; j < 4; j++) {
      redS[rh][cs][q * 4 + j] = s0[j];
      redQ[rh][cs][q * 4 + j] = s1[j];
    }
  }
  __syncthreads();
  float mean[4], rstd[4];
  #pragma unroll
  for (int j = 0; j < 4; j++) {
    int r = q * 4 + j;
    float S = redS[rh][0][r] + redS[rh][1][r] + redS[rh][2][r] + redS[rh][3][r];
    float Q = redQ[rh][0][r] + redQ[rh][1][r] + redQ[rh][2][r] + redQ[rh][3][r];
    float mu  = S * (1.0f / 256.0f);
    float var = Q * (1.0f / 256.0f) - mu * mu;
    mean[j] = mu;
    rstd[j] = rsqrtf(var + 1e-5f);
  }

  if (STAGE == 1) {
    #pragma unroll
    for (int ct = 0; ct < 4; ct++) {
      int c = wc + ct * 16 + p;
      float gg = sG[c], bb = sB[c];
      #pragma unroll
      for (int j = 0; j < 4; j++) {
        float v = (acc[ct][j] - mean[j]) * rstd[j] * gg + bb;
        v = fmaxf(v, 0.0f);
        Hout[(size_t)(m0 + rh16 + q * 4 + j) * 256 + c] = f2bf(v);
      }
    }
  } else {
    float ls[4] = {0,0,0,0};
    #pragma unroll
    for (int ct = 0; ct < 4; ct++) {
      int c = wc + ct * 16 + p;
      float gg = sG[c], bb = sB[c], ww = sLw[c];
      #pragma unroll
      for (int j = 0; j < 4; j++) {
        float v = (acc[ct][j] - mean[j]) * rstd[j] * gg + bb;
        v = fmaxf(v, 0.0f);
        ls[j] += v * ww;
      }
    }
    #pragma unroll
    for (int m = 1; m <= 8; m <<= 1) {
      #pragma unroll
      for (int j = 0; j < 4; j++) ls[j] += __shfl_xor(ls[j], m);
    }
    __syncthreads();
    if (p == 0) {
      #pragma unroll
      for (int j = 0; j < 4; j++) redS[rh][cs][q * 4 + j] = ls[j];
    }
    __syncthreads();
    if (t < 32) {
      int r2 = t >> 4, ri = t & 15;
      float dv = fmaxf(redS[r2][0][ri] + redS[r2][1][ri] +
                       redS[r2][2][ri] + redS[r2][3][ri] + lb[0], 0.0f);
      dpo[m0 + t] = dv;
    }
  }
}

// ---------------------------------------------------------------------------
// 512-thread LR body (proven R6/R7): 256 lr-blocks, 256 T-rows each.
// ---------------------------------------------------------------------------
__device__ __forceinline__ void lr_body512(
    const int lrblk, const int t,
    const float* __restrict__ X, const int* __restrict__ tgt,
    float* __restrict__ out, int* sc, int* sidx)
{
  const int n  = lrblk >> 4;
  const int t0 = (lrblk & 15) * 256;

  sc[t] = tgt[n * L_S + t];
  __syncthreads();
  for (int off = 1; off < L_S; off <<= 1) {
    int v = (t >= off) ? sc[t - off] : 0;
    __syncthreads();
    sc[t] += v;
    __syncthreads();
  }
  const int total = sc[L_S - 1];
  if (t < 256) {
    int tt = t0 + t;
    int lo = 0, hi = L_S;
    while (lo < hi) {
      int mid = (lo + hi) >> 1;
      if (sc[mid] <= tt) lo = mid + 1; else hi = mid;
    }
    sidx[t] = (tt < total) ? lo : -1;
  }
  __syncthreads();

  #pragma unroll
  for (int i = 0; i < 32; i++) {
    int u   = t + i * 512;
    int dg  = u & 63;
    int tr  = u >> 6;
    int idx = sidx[tr];
    float4 v = make_float4(0.f, 0.f, 0.f, 0.f);
    if (idx >= 0)
      v = *(const float4*)(X + (((size_t)(n * L_S + idx)) << 8) + dg * 4);
    *(float4*)(out + (((size_t)(n * T_MEL + t0 + tr)) << 8) + dg * 4) = v;
  }
}

// ---------------------------------------------------------------------------
// WS-path kernels (direct-B).
// ---------------------------------------------------------------------------
template<int STAGE>
__global__ __launch_bounds__(512)
void conv_dir_kernel(const float* __restrict__ Xf, const u16* __restrict__ Xh,
                     const u16* __restrict__ Wp,
                     const float* __restrict__ cb,  const float* __restrict__ lgm,
                     const float* __restrict__ lbt, const float* __restrict__ lw,
                     const float* __restrict__ lb,  u16* __restrict__ Hout,
                     float* __restrict__ dpo)
{
  __shared__ __align__(16) u16 As[34 * 264 + 8];
  __shared__ float sBias[256], sG[256], sB[256], sLw[256];
  __shared__ float redS[2][4][16], redQ[2][4][16];
  conv_body_dir<STAGE>((int)blockIdx.x, (int)threadIdx.x, Xf, Xh, Wp, cb, lgm,
                       lbt, lw, lb, Hout, dpo, As, sBias, sG, sB, sLw, redS, redQ);
}

// Fused: blocks 0..255 = conv stage 1 (direct-B); blocks 256..511 = lr.
__global__ __launch_bounds__(512)
void conv1_lr_dir_kernel(const float* __restrict__ x, const u16* __restrict__ Wp,
                         const float* __restrict__ cb,  const float* __restrict__ lgm,
                         const float* __restrict__ lbt, u16* __restrict__ Hout,
                         const int* __restrict__ tgt, float* __restrict__ out)
{
  __shared__ __align__(16) u16 As[34 * 264 + 8];
  __shared__ float sBias[256], sG[256], sB[256], sLw[256];
  __shared__ float redS[2][4][16], redQ[2][4][16];
  __shared__ int  sc[512];
  __shared__ int  sidx[256];

  const int blk = (int)blockIdx.x, t = (int)threadIdx.x;
  if (blk < 256) {
    conv_body_dir<1>(blk, t, x, nullptr, Wp, cb, lgm, lbt, nullptr, nullptr,
                     Hout, nullptr, As, sBias, sG, sB, sLw, redS, redQ);
  } else {
    lr_body512(blk - 256, t, x, tgt, out, sc, sidx);
  }
}

// ---------------------------------------------------------------------------
// FALLBACK path: exact R8 kernels (proven 121.2us).
// ---------------------------------------------------------------------------
template<int STAGE>
__device__ __forceinline__ void conv_body(
    const int blk, const int t,
    const float* __restrict__ Xf, const u16* __restrict__ Xh,
    const u16* __restrict__ Wp,
    const float* __restrict__ cb,  const float* __restrict__ lgm,
    const float* __restrict__ lbt, const float* __restrict__ lw,
    const float* __restrict__ lb,  u16* __restrict__ Hout,
    float* __restrict__ dpo,
    u16* As, u16* Bs, float* sBias, float* sG, float* sB, float* sLw,
    float (*redS)[4][16], float (*redQ)[4][16])
{
  if (t < 256) {
    sBias[t] = cb[t];
    sG[t]    = lgm[t];
    sB[t]    = lbt[t];
    if (STAGE == 2) sLw[t] = lw[t];
  }

  const int m0   = blk * 32;
  const int n    = m0 >> 9;
  const int l0   = m0 & 511;
  const int wave = t >> 6, lane = t & 63;
  const int cs   = wave & 3;
  const int rh   = wave >> 2;
  const int wc   = cs * 64;
  const int rh16 = rh * 16;
  const int p    = lane & 15, q = lane >> 4;

  f32x4 acc[4];
  #pragma unroll
  for (int i = 0; i < 4; i++) acc[i] = (f32x4){0.f, 0.f, 0.f, 0.f};

  auto LDW = [&](int s, uint4 &r0, uint4 &r1) {
    const u16* src = Wp + ((size_t)s << 13);
    r0 = *(const uint4*)(src + (t << 3));
    r1 = *(const uint4*)(src + ((t + 512) << 3));
  };
  auto WRB = [&](int buf, const uint4 &r0, const uint4 &r1) {
    *(uint4*)(Bs + (buf << 13) + (t << 3))         = r0;
    *(uint4*)(Bs + (buf << 13) + ((t + 512) << 3)) = r1;
  };
  auto MF = [&](int buf, int s) {
    const u16* bs = Bs + (buf << 13);
    const int tap = s >> 3, dbase = (s & 7) << 5;
    bf16x8 af = *(const bf16x8*)(As + (rh16 + p + tap) * 264 + dbase + (q << 3));
    #pragma unroll
    for (int ct = 0; ct < 4; ct++) {
      bf16x8 bfr = *(const bf16x8*)(bs + ((wc + ct * 16 + p) << 5) + (q << 3));
      acc[ct] = __builtin_amdgcn_mfma_f32_16x16x32_bf16(af, bfr, acc[ct], 0, 0, 0);
    }
  };

  uint4 e0, e1, o0, o1;
  LDW(0, e0, e1);
  LDW(1, o0, o1);

  for (int c = t; c < 1088; c += 512) {
    int row  = c >> 5;
    int col8 = c & 31;
    int l    = l0 + row - 1;
    uint4 val;
    if ((unsigned)l < 512u) {
      if (STAGE == 1) {
        const float* src = Xf + (((size_t)((n << 9) + l)) << 8) + (col8 << 3);
        float4 v0 = *(const float4*)src;
        float4 v1 = *(const float4*)(src + 4);
        bf16x8 pk = pack8(v0, v1);
        __builtin_memcpy(&val, &pk, 16);
      } else {
        val = *(const uint4*)(Xh + (((size_t)((n << 9) + l)) << 8) + (col8 << 3));
      }
    } else {
      val = make_uint4(0u, 0u, 0u, 0u);
    }
    *(uint4*)(As + row * 264 + (col8 << 3)) = val;
  }
  WRB(0, e0, e1);
  __syncthreads();

  for (int s2 = 0; s2 < 24; s2 += 2) {
    MF(0, s2);
    if (s2 + 2 < 24) LDW(s2 + 2, e0, e1);
    WRB(1, o0, o1);
    __syncthreads();
    MF(1, s2 + 1);
    if (s2 + 3 < 24) LDW(s2 + 3, o0, o1);
    if (s2 + 2 < 24) WRB(0, e0, e1);
    __syncthreads();
  }

  float s0[4] = {0,0,0,0}, s1[4] = {0,0,0,0};
  #pragma unroll
  for (int ct = 0; ct < 4; ct++) {
    float bias = sBias[wc + ct * 16 + p];
    #pragma unroll
    for (int j = 0; j < 4; j++) {
      float v = acc[ct][j] + bias;
      acc[ct][j] = v;
      s0[j] += v;
      s1[j] += v * v;
    }
  }
  #pragma unroll
  for (int m = 1; m <= 8; m <<= 1) {
    #pragma unroll
    for (int j = 0; j < 4; j++) {
      s0[j] += __shfl_xor(s0[j], m);
      s1[j] += __shfl_xor(s1[j], m);
    }
  }
  if (p == 0) {
    #pragma unroll
    for (int j = 0; j < 4; j++) {
      redS[rh][cs][q * 4 + j] = s0[j];
      redQ[rh][cs][q * 4 + j] = s1[j];
    }
  }
  __syncthreads();
  float mean[4], rstd[4];
  #pragma unroll
  for (int j = 0; j < 4; j++) {
    int r = q * 4 + j;
    float S = redS[rh][0][r] + redS[rh][1][r] + redS[rh][2][r] + redS[rh][3][r];
    float Q = redQ[rh][0][r] + redQ[rh][1][r] + redQ[rh][2][r] + redQ[rh][3][r];
    float mu  = S * (1.0f / 256.0f);
    float var = Q * (1.0f / 256.0f) - mu * mu;
    mean[j] = mu;
    rstd[j] = rsqrtf(var + 1e-5f);
  }

  if (STAGE == 1) {
    #pragma unroll
    for (int ct = 0; ct < 4; ct++) {
      int c = wc + ct * 16 + p;
      float gg = sG[c], bb = sB[c];
      #pragma unroll
      for (int j = 0; j < 4; j++) {
        float v = (acc[ct][j] - mean[j]) * rstd[j] * gg + bb;
        v = fmaxf(v, 0.0f);
        Hout[(size_t)(m0 + rh16 + q * 4 + j) * 256 + c] = f2bf(v);
      }
    }
  } else {
    float ls[4] = {0,0,0,0};
    #pragma unroll
    for (int ct = 0; ct < 4; ct++) {
      int c = wc + ct * 16 + p;
      float gg = sG[c], bb = sB[c], ww = sLw[c];
      #pragma unroll
      for (int j = 0; j < 4; j++) {
        float v = (acc[ct][j] - mean[j]) * rstd[j] * gg + bb;
        v = fmaxf(v, 0.0f);
        ls[j] += v * ww;
      }
    }
    #pragma unroll
    for (int m = 1; m <= 8; m <<= 1) {
      #pragma unroll
      for (int j = 0; j < 4; j++) ls[j] += __shfl_xor(ls[j], m);
    }
    __syncthreads();
    if (p == 0) {
      #pragma unroll
      for (int j = 0; j < 4; j++) redS[rh][cs][q * 4 + j] = ls[j];
    }
    __syncthreads();
    if (t < 32) {
      int r2 = t >> 4, ri = t & 15;
      float dv = fmaxf(redS[r2][0][ri] + redS[r2][1][ri] +
                       redS[r2][2][ri] + redS[r2][3][ri] + lb[0], 0.0f);
      dpo[m0 + t] = dv;
    }
  }
}

template<int STAGE>
__global__ __launch_bounds__(512)
void conv_ln_kernel(const float* __restrict__ Xf, const u16* __restrict__ Xh,
                    const u16* __restrict__ Wp,
                    const float* __restrict__ cb,  const float* __restrict__ lgm,
                    const float* __restrict__ lbt, const float* __restrict__ lw,
                    const float* __restrict__ lb,  u16* __restrict__ Hout,
                    float* __restrict__ dpo)
{
  __shared__ __align__(16) u16 As[34 * 264 + 8];
  __shared__ __align__(16) u16 Bs[2 * 8192];
  __shared__ float sBias[256], sG[256], sB[256], sLw[256];
  __shared__ float redS[2][4][16], redQ[2][4][16];
  conv_body<STAGE>((int)blockIdx.x, (int)threadIdx.x, Xf, Xh, Wp, cb, lgm, lbt,
                   lw, lb, Hout, dpo, As, Bs, sBias, sG, sB, sLw, redS, redQ);
}

__global__ __launch_bounds__(256)
void lr_kernel(const float* __restrict__ X, const int* __restrict__ tgt,
               float* __restrict__ out) {
  __shared__ int c[L_S];
  __shared__ int sidx[TBLK];
  const int t  = threadIdx.x;
  const int n  = blockIdx.x >> 5;
  const int t0 = (blockIdx.x & 31) * TBLK;

  c[t]       = tgt[n * L_S + t];
  c[t + 256] = tgt[n * L_S + t + 256];
  __syncthreads();
  for (int off = 1; off < L_S; off <<= 1) {
    int v0 = (t >= off) ? c[t - off] : 0;
    int i1 = t + 256;
    int v1 = (i1 >= off) ? c[i1 - off] : 0;
    __syncthreads();
    c[t]  += v0;
    c[i1] += v1;
    __syncthreads();
  }
  const int total = c[L_S - 1];
  if (t < TBLK) {
    int tt = t0 + t;
    int lo = 0, hi = L_S;
    while (lo < hi) {
      int mid = (lo + hi) >> 1;
      if (c[mid] <= tt) lo = mid + 1; else hi = mid;
    }
    sidx[t] = (tt < total) ? lo : -1;
  }
  __syncthreads();

  #pragma unroll
  for (int i = 0; i < 32; i++) {
    int u   = t + i * 256;
    int dg  = u & 63;
    int tr  = u >> 6;
    int idx = sidx[tr];
    float4 v = make_float4(0.f, 0.f, 0.f, 0.f);
    if (idx >= 0)
      v = *(const float4*)(X + (((size_t)(n * L_S + idx)) << 8) + dg * 4);
    *(float4*)(out + (((size_t)(n * T_MEL + t0 + tr)) << 8) + dg * 4) = v;
  }
}

// ---------------------------------------------------------------------------
extern "C" void kernel_launch(void* const* d_in, const int* in_sizes, int n_in,
                              void* d_out, int out_size, void* d_ws, size_t ws_size,
                              hipStream_t stream) {
  (void)in_sizes; (void)n_in; (void)out_size;

  const float* x   = (const float*)d_in[0];
  const float* w1  = (const float*)d_in[1];
  const float* b1  = (const float*)d_in[2];
  const float* g1  = (const float*)d_in[3];
  const float* be1 = (const float*)d_in[4];
  const float* w2  = (const float*)d_in[5];
  const float* b2  = (const float*)d_in[6];
  const float* g2  = (const float*)d_in[7];
  const float* be2 = (const float*)d_in[8];
  const float* lw  = (const float*)d_in[9];
  const float* lb  = (const float*)d_in[10];
  const int*   tgt = (const int*)d_in[11];

  float* out = (float*)d_out;
  float* dpo = out + OUT_ELEMS;

  const size_t need = (H1_ELEMS + 2 * (size_t)WP_ELEMS) * sizeof(u16); // ~5 MB

  if (d_ws != nullptr && ws_size >= need) {
    // Direct-B, no-barrier K-loop; lr overlaps conv1 in one dispatch.
    u16* h1  = (u16*)d_ws;
    u16* wp1 = h1 + H1_ELEMS;
    u16* wp2 = wp1 + WP_ELEMS;
    pack_kernel<<<768, 256, 0, stream>>>(w1, w2, wp1, wp2);
    conv1_lr_dir_kernel<<<512, 512, 0, stream>>>(x, wp1, b1, g1, be1, h1, tgt, out);
    conv_dir_kernel<2><<<M_TOT / 32, 512, 0, stream>>>(
        nullptr, h1, wp2, b2, g2, be2, lw, lb, nullptr, dpo);
  } else {
    // Fallback = exact R8 (proven 121.2us): scratch in out, lr LAST.
    u16* h1  = (u16*)d_out;
    u16* wp1 = h1 + H1_ELEMS;
    u16* wp2 = wp1 + WP_ELEMS;
    pack_kernel<<<768, 256, 0, stream>>>(w1, w2, wp1, wp2);
    conv_ln_kernel<1><<<M_TOT / 32, 512, 0, stream>>>(
        x, nullptr, wp1, b1, g1, be1, nullptr, nullptr, h1, nullptr);
    conv_ln_kernel<2><<<M_TOT / 32, 512, 0, stream>>>(
        nullptr, h1, wp2, b2, g2, be2, lw, lb, nullptr, dpo);
    lr_kernel<<<N_B * (T_MEL / TBLK), 256, 0, stream>>>(x, tgt, out);
  }
}

// Round 14
// 129.847 us; speedup vs baseline: 1.0269x; 1.0269x over previous
//
#include <hip/hip_runtime.h>
#include <hip/hip_bf16.h>

using u16 = unsigned short;
typedef __bf16 bf16x8 __attribute__((ext_vector_type(8)));
typedef float f32x4 __attribute__((ext_vector_type(4)));

#define N_B   16
#define L_S   512
#define D_F   256
#define T_MEL 4096
#define M_TOT (N_B * L_S)
#define OUT_ELEMS ((size_t)N_B * T_MEL * D_F)   // fp32 elems
#define H1_ELEMS  ((size_t)M_TOT * D_F)         // bf16 elems
#define WP_ELEMS  (24 * 8192)                   // packed weight elems per conv
#define TBLK 128

__device__ __forceinline__ u16 f2bf(float f) {
  __hip_bfloat16 h = __float2bfloat16(f);
  return *(u16*)&h;
}

__device__ __forceinline__ bf16x8 pack8(float4 v0, float4 v1) {
  union { bf16x8 h; u16 u[8]; } r;
  r.u[0] = f2bf(v0.x); r.u[1] = f2bf(v0.y); r.u[2] = f2bf(v0.z); r.u[3] = f2bf(v0.w);
  r.u[4] = f2bf(v1.x); r.u[5] = f2bf(v1.y); r.u[6] = f2bf(v1.z); r.u[7] = f2bf(v1.w);
  return r.h;
}

// ---------------------------------------------------------------------------
// Weight pack: wp[s][f][ki] = w[f][(s&7)*32+ki][s>>3]  (proven indexing).
// ---------------------------------------------------------------------------
__global__ __launch_bounds__(256)
void pack_kernel(const float* __restrict__ w1, const float* __restrict__ w2,
                 u16* __restrict__ wp1, u16* __restrict__ wp2) {
  int o   = (int)blockIdx.x * 256 + (int)threadIdx.x;   // 0..196607
  int s   = o >> 13;
  int rem = o & 8191;
  int f   = rem >> 5;
  int ki  = rem & 31;
  int d   = ((s & 7) << 5) + ki;
  int tap = s >> 3;
  int src = f * 768 + d * 3 + tap;
  wp1[o] = f2bf(w1[src]);
  wp2[o] = f2bf(w2[src]);
}

// ---------------------------------------------------------------------------
// GLL conv body (round 14): R8 schedule/layout/epilogue VERBATIM, with B
// staging via __builtin_amdgcn_global_load_lds width=16 (Common-mistake #1:
// compiler never auto-emits it). Replaces per-step {2x global->reg, 2x
// ds_write_b128, reg-dep waitcnts} with 2 async DMA ops. Layout is the
// compatible pattern: thread t's 16B lands at wave-uniform base + lane*16
// (linear, unpadded). Issue targets buf[other] at the top of each step
// (prior readers separated by last barrier); the end-of-step __syncthreads
// vmcnt(0) is the landing fence. A staged once in LDS (proven).
// ---------------------------------------------------------------------------
template<int STAGE>
__device__ __forceinline__ void conv_body_gll(
    const int blk, const int t,
    const float* __restrict__ Xf, const u16* __restrict__ Xh,
    const u16* __restrict__ Wp,
    const float* __restrict__ cb,  const float* __restrict__ lgm,
    const float* __restrict__ lbt, const float* __restrict__ lw,
    const float* __restrict__ lb,  u16* __restrict__ Hout,
    float* __restrict__ dpo,
    u16* As, u16* Bs, float* sBias, float* sG, float* sB, float* sLw,
    float (*redS)[4][16], float (*redQ)[4][16])
{
  if (t < 256) {
    sBias[t] = cb[t];
    sG[t]    = lgm[t];
    sB[t]    = lbt[t];
    if (STAGE == 2) sLw[t] = lw[t];
  }

  const int m0   = blk * 32;
  const int n    = m0 >> 9;
  const int l0   = m0 & 511;
  const int wave = t >> 6, lane = t & 63;
  const int cs   = wave & 3;
  const int rh   = wave >> 2;
  const int wc   = cs * 64;
  const int rh16 = rh * 16;
  const int p    = lane & 15, q = lane >> 4;
  const int wv64 = wave << 6;            // wave-uniform lane-0 thread id

  f32x4 acc[4];
  #pragma unroll
  for (int i = 0; i < 4; i++) acc[i] = (f32x4){0.f, 0.f, 0.f, 0.f};

  // async global->LDS staging: 2 x 16B per thread, linear layout
  auto GLL = [&](int s, int buf) {
    const u16* src = Wp + ((size_t)s << 13);
    __builtin_amdgcn_global_load_lds(
        (const __attribute__((address_space(1))) void*)(src + (t << 3)),
        (__attribute__((address_space(3))) void*)(Bs + (buf << 13) + (wv64 << 3)),
        16, 0, 0);
    __builtin_amdgcn_global_load_lds(
        (const __attribute__((address_space(1))) void*)(src + ((t + 512) << 3)),
        (__attribute__((address_space(3))) void*)(Bs + (buf << 13) + ((wv64 + 512) << 3)),
        16, 0, 0);
  };
  auto MF = [&](int buf, int s) {
    const u16* bs = Bs + (buf << 13);
    const int tap = s >> 3, dbase = (s & 7) << 5;
    bf16x8 af = *(const bf16x8*)(As + (rh16 + p + tap) * 264 + dbase + (q << 3));
    #pragma unroll
    for (int ct = 0; ct < 4; ct++) {
      bf16x8 bfr = *(const bf16x8*)(bs + ((wc + ct * 16 + p) << 5) + (q << 3));
      acc[ct] = __builtin_amdgcn_mfma_f32_16x16x32_bf16(af, bfr, acc[ct], 0, 0, 0);
    }
  };

  // ---- prologue: issue GLL(0 -> buf0); stage A; barrier lands buf0 ----
  GLL(0, 0);

  for (int c = t; c < 1088; c += 512) {   // stage A once (34 x 256, bf16)
    int row  = c >> 5;
    int col8 = c & 31;
    int l    = l0 + row - 1;
    uint4 val;
    if ((unsigned)l < 512u) {
      if (STAGE == 1) {
        const float* src = Xf + (((size_t)((n << 9) + l)) << 8) + (col8 << 3);
        float4 v0 = *(const float4*)src;
        float4 v1 = *(const float4*)(src + 4);
        bf16x8 pk = pack8(v0, v1);
        __builtin_memcpy(&val, &pk, 16);
      } else {
        val = *(const uint4*)(Xh + (((size_t)((n << 9) + l)) << 8) + (col8 << 3));
      }
    } else {
      val = make_uint4(0u, 0u, 0u, 0u);
    }
    *(uint4*)(As + row * 264 + (col8 << 3)) = val;
  }
  __syncthreads();                        // buf0 landed (vmcnt0) + A visible

  // ---- K-loop: R8 shape, GLL staging, one barrier per step ----
  for (int s2 = 0; s2 < 24; s2 += 2) {
    GLL(s2 + 1, 1);                       // buf1: readers were step s2-1
    MF(0, s2);
    __syncthreads();                      // buf1 landed
    if (s2 + 2 < 24) GLL(s2 + 2, 0);      // buf0: readers were step s2
    MF(1, s2 + 1);
    __syncthreads();                      // buf0 landed
  }

  // ---- epilogue: R8 VERBATIM ----
  float s0[4] = {0,0,0,0}, s1[4] = {0,0,0,0};
  #pragma unroll
  for (int ct = 0; ct < 4; ct++) {
    float bias = sBias[wc + ct * 16 + p];
    #pragma unroll
    for (int j = 0; j < 4; j++) {
      float v = acc[ct][j] + bias;
      acc[ct][j] = v;
      s0[j] += v;
      s1[j] += v * v;
    }
  }
  #pragma unroll
  for (int m = 1; m <= 8; m <<= 1) {
    #pragma unroll
    for (int j = 0; j < 4; j++) {
      s0[j] += __shfl_xor(s0[j], m);
      s1[j] += __shfl_xor(s1[j], m);
    }
  }
  if (p == 0) {
    #pragma unroll
    for (int j = 0; j < 4; j++) {
      redS[rh][cs][q * 4 + j] = s0[j];
      redQ[rh][cs][q * 4 + j] = s1[j];
    }
  }
  __syncthreads();
  float mean[4], rstd[4];
  #pragma unroll
  for (int j = 0; j < 4; j++) {
    int r = q * 4 + j;
    float S = redS[rh][0][r] + redS[rh][1][r] + redS[rh][2][r] + redS[rh][3][r];
    float Q = redQ[rh][0][r] + redQ[rh][1][r] + redQ[rh][2][r] + redQ[rh][3][r];
    float mu  = S * (1.0f / 256.0f);
    float var = Q * (1.0f / 256.0f) - mu * mu;
    mean[j] = mu;
    rstd[j] = rsqrtf(var + 1e-5f);
  }

  if (STAGE == 1) {
    #pragma unroll
    for (int ct = 0; ct < 4; ct++) {
      int c = wc + ct * 16 + p;
      float gg = sG[c], bb = sB[c];
      #pragma unroll
      for (int j = 0; j < 4; j++) {
        float v = (acc[ct][j] - mean[j]) * rstd[j] * gg + bb;
        v = fmaxf(v, 0.0f);
        Hout[(size_t)(m0 + rh16 + q * 4 + j) * 256 + c] = f2bf(v);
      }
    }
  } else {
    float ls[4] = {0,0,0,0};
    #pragma unroll
    for (int ct = 0; ct < 4; ct++) {
      int c = wc + ct * 16 + p;
      float gg = sG[c], bb = sB[c], ww = sLw[c];
      #pragma unroll
      for (int j = 0; j < 4; j++) {
        float v = (acc[ct][j] - mean[j]) * rstd[j] * gg + bb;
        v = fmaxf(v, 0.0f);
        ls[j] += v * ww;
      }
    }
    #pragma unroll
    for (int m = 1; m <= 8; m <<= 1) {
      #pragma unroll
      for (int j = 0; j < 4; j++) ls[j] += __shfl_xor(ls[j], m);
    }
    __syncthreads();
    if (p == 0) {
      #pragma unroll
      for (int j = 0; j < 4; j++) redS[rh][cs][q * 4 + j] = ls[j];
    }
    __syncthreads();
    if (t < 32) {
      int r2 = t >> 4, ri = t & 15;
      float dv = fmaxf(redS[r2][0][ri] + redS[r2][1][ri] +
                       redS[r2][2][ri] + redS[r2][3][ri] + lb[0], 0.0f);
      dpo[m0 + t] = dv;
    }
  }
}

// ---------------------------------------------------------------------------
// 512-thread LR body (proven R6/R7): 256 lr-blocks, 256 T-rows each.
// ---------------------------------------------------------------------------
__device__ __forceinline__ void lr_body512(
    const int lrblk, const int t,
    const float* __restrict__ X, const int* __restrict__ tgt,
    float* __restrict__ out, int* sc, int* sidx)
{
  const int n  = lrblk >> 4;
  const int t0 = (lrblk & 15) * 256;

  sc[t] = tgt[n * L_S + t];
  __syncthreads();
  for (int off = 1; off < L_S; off <<= 1) {
    int v = (t >= off) ? sc[t - off] : 0;
    __syncthreads();
    sc[t] += v;
    __syncthreads();
  }
  const int total = sc[L_S - 1];
  if (t < 256) {
    int tt = t0 + t;
    int lo = 0, hi = L_S;
    while (lo < hi) {
      int mid = (lo + hi) >> 1;
      if (sc[mid] <= tt) lo = mid + 1; else hi = mid;
    }
    sidx[t] = (tt < total) ? lo : -1;
  }
  __syncthreads();

  #pragma unroll
  for (int i = 0; i < 32; i++) {
    int u   = t + i * 512;
    int dg  = u & 63;
    int tr  = u >> 6;
    int idx = sidx[tr];
    float4 v = make_float4(0.f, 0.f, 0.f, 0.f);
    if (idx >= 0)
      v = *(const float4*)(X + (((size_t)(n * L_S + idx)) << 8) + dg * 4);
    *(float4*)(out + (((size_t)(n * T_MEL + t0 + tr)) << 8) + dg * 4) = v;
  }
}

// ---------------------------------------------------------------------------
// WS-path kernels (GLL staging).
// ---------------------------------------------------------------------------
template<int STAGE>
__global__ __launch_bounds__(512)
void conv_gll_kernel(const float* __restrict__ Xf, const u16* __restrict__ Xh,
                     const u16* __restrict__ Wp,
                     const float* __restrict__ cb,  const float* __restrict__ lgm,
                     const float* __restrict__ lbt, const float* __restrict__ lw,
                     const float* __restrict__ lb,  u16* __restrict__ Hout,
                     float* __restrict__ dpo)
{
  __shared__ __align__(16) u16 As[34 * 264 + 8];
  __shared__ __align__(16) u16 Bs[2 * 8192];
  __shared__ float sBias[256], sG[256], sB[256], sLw[256];
  __shared__ float redS[2][4][16], redQ[2][4][16];
  conv_body_gll<STAGE>((int)blockIdx.x, (int)threadIdx.x, Xf, Xh, Wp, cb, lgm,
                       lbt, lw, lb, Hout, dpo, As, Bs, sBias, sG, sB, sLw,
                       redS, redQ);
}

// Fused: blocks 0..255 = conv stage 1 (GLL); blocks 256..511 = lr.
__global__ __launch_bounds__(512)
void conv1_lr_gll_kernel(const float* __restrict__ x, const u16* __restrict__ Wp,
                         const float* __restrict__ cb,  const float* __restrict__ lgm,
                         const float* __restrict__ lbt, u16* __restrict__ Hout,
                         const int* __restrict__ tgt, float* __restrict__ out)
{
  __shared__ __align__(16) u16 As[34 * 264 + 8];
  __shared__ __align__(16) u16 Bs[2 * 8192];
  __shared__ float sBias[256], sG[256], sB[256], sLw[256];
  __shared__ float redS[2][4][16], redQ[2][4][16];
  __shared__ int  sc[512];
  __shared__ int  sidx[256];

  const int blk = (int)blockIdx.x, t = (int)threadIdx.x;
  if (blk < 256) {
    conv_body_gll<1>(blk, t, x, nullptr, Wp, cb, lgm, lbt, nullptr, nullptr,
                     Hout, nullptr, As, Bs, sBias, sG, sB, sLw, redS, redQ);
  } else {
    lr_body512(blk - 256, t, x, tgt, out, sc, sidx);
  }
}

// ---------------------------------------------------------------------------
// FALLBACK path: exact R8 kernels (proven 121.2us).
// ---------------------------------------------------------------------------
template<int STAGE>
__device__ __forceinline__ void conv_body(
    const int blk, const int t,
    const float* __restrict__ Xf, const u16* __restrict__ Xh,
    const u16* __restrict__ Wp,
    const float* __restrict__ cb,  const float* __restrict__ lgm,
    const float* __restrict__ lbt, const float* __restrict__ lw,
    const float* __restrict__ lb,  u16* __restrict__ Hout,
    float* __restrict__ dpo,
    u16* As, u16* Bs, float* sBias, float* sG, float* sB, float* sLw,
    float (*redS)[4][16], float (*redQ)[4][16])
{
  if (t < 256) {
    sBias[t] = cb[t];
    sG[t]    = lgm[t];
    sB[t]    = lbt[t];
    if (STAGE == 2) sLw[t] = lw[t];
  }

  const int m0   = blk * 32;
  const int n    = m0 >> 9;
  const int l0   = m0 & 511;
  const int wave = t >> 6, lane = t & 63;
  const int cs   = wave & 3;
  const int rh   = wave >> 2;
  const int wc   = cs * 64;
  const int rh16 = rh * 16;
  const int p    = lane & 15, q = lane >> 4;

  f32x4 acc[4];
  #pragma unroll
  for (int i = 0; i < 4; i++) acc[i] = (f32x4){0.f, 0.f, 0.f, 0.f};

  auto LDW = [&](int s, uint4 &r0, uint4 &r1) {
    const u16* src = Wp + ((size_t)s << 13);
    r0 = *(const uint4*)(src + (t << 3));
    r1 = *(const uint4*)(src + ((t + 512) << 3));
  };
  auto WRB = [&](int buf, const uint4 &r0, const uint4 &r1) {
    *(uint4*)(Bs + (buf << 13) + (t << 3))         = r0;
    *(uint4*)(Bs + (buf << 13) + ((t + 512) << 3)) = r1;
  };
  auto MF = [&](int buf, int s) {
    const u16* bs = Bs + (buf << 13);
    const int tap = s >> 3, dbase = (s & 7) << 5;
    bf16x8 af = *(const bf16x8*)(As + (rh16 + p + tap) * 264 + dbase + (q << 3));
    #pragma unroll
    for (int ct = 0; ct < 4; ct++) {
      bf16x8 bfr = *(const bf16x8*)(bs + ((wc + ct * 16 + p) << 5) + (q << 3));
      acc[ct] = __builtin_amdgcn_mfma_f32_16x16x32_bf16(af, bfr, acc[ct], 0, 0, 0);
    }
  };

  uint4 e0, e1, o0, o1;
  LDW(0, e0, e1);
  LDW(1, o0, o1);

  for (int c = t; c < 1088; c += 512) {
    int row  = c >> 5;
    int col8 = c & 31;
    int l    = l0 + row - 1;
    uint4 val;
    if ((unsigned)l < 512u) {
      if (STAGE == 1) {
        const float* src = Xf + (((size_t)((n << 9) + l)) << 8) + (col8 << 3);
        float4 v0 = *(const float4*)src;
        float4 v1 = *(const float4*)(src + 4);
        bf16x8 pk = pack8(v0, v1);
        __builtin_memcpy(&val, &pk, 16);
      } else {
        val = *(const uint4*)(Xh + (((size_t)((n << 9) + l)) << 8) + (col8 << 3));
      }
    } else {
      val = make_uint4(0u, 0u, 0u, 0u);
    }
    *(uint4*)(As + row * 264 + (col8 << 3)) = val;
  }
  WRB(0, e0, e1);
  __syncthreads();

  for (int s2 = 0; s2 < 24; s2 += 2) {
    MF(0, s2);
    if (s2 + 2 < 24) LDW(s2 + 2, e0, e1);
    WRB(1, o0, o1);
    __syncthreads();
    MF(1, s2 + 1);
    if (s2 + 3 < 24) LDW(s2 + 3, o0, o1);
    if (s2 + 2 < 24) WRB(0, e0, e1);
    __syncthreads();
  }

  float s0[4] = {0,0,0,0}, s1[4] = {0,0,0,0};
  #pragma unroll
  for (int ct = 0; ct < 4; ct++) {
    float bias = sBias[wc + ct * 16 + p];
    #pragma unroll
    for (int j = 0; j < 4; j++) {
      float v = acc[ct][j] + bias;
      acc[ct][j] = v;
      s0[j] += v;
      s1[j] += v * v;
    }
  }
  #pragma unroll
  for (int m = 1; m <= 8; m <<= 1) {
    #pragma unroll
    for (int j = 0; j < 4; j++) {
      s0[j] += __shfl_xor(s0[j], m);
      s1[j] += __shfl_xor(s1[j], m);
    }
  }
  if (p == 0) {
    #pragma unroll
    for (int j = 0; j < 4; j++) {
      redS[rh][cs][q * 4 + j] = s0[j];
      redQ[rh][cs][q * 4 + j] = s1[j];
    }
  }
  __syncthreads();
  float mean[4], rstd[4];
  #pragma unroll
  for (int j = 0; j < 4; j++) {
    int r = q * 4 + j;
    float S = redS[rh][0][r] + redS[rh][1][r] + redS[rh][2][r] + redS[rh][3][r];
    float Q = redQ[rh][0][r] + redQ[rh][1][r] + redQ[rh][2][r] + redQ[rh][3][r];
    float mu  = S * (1.0f / 256.0f);
    float var = Q * (1.0f / 256.0f) - mu * mu;
    mean[j] = mu;
    rstd[j] = rsqrtf(var + 1e-5f);
  }

  if (STAGE == 1) {
    #pragma unroll
    for (int ct = 0; ct < 4; ct++) {
      int c = wc + ct * 16 + p;
      float gg = sG[c], bb = sB[c];
      #pragma unroll
      for (int j = 0; j < 4; j++) {
        float v = (acc[ct][j] - mean[j]) * rstd[j] * gg + bb;
        v = fmaxf(v, 0.0f);
        Hout[(size_t)(m0 + rh16 + q * 4 + j) * 256 + c] = f2bf(v);
      }
    }
  } else {
    float ls[4] = {0,0,0,0};
    #pragma unroll
    for (int ct = 0; ct < 4; ct++) {
      int c = wc + ct * 16 + p;
      float gg = sG[c], bb = sB[c], ww = sLw[c];
      #pragma unroll
      for (int j = 0; j < 4; j++) {
        float v = (acc[ct][j] - mean[j]) * rstd[j] * gg + bb;
        v = fmaxf(v, 0.0f);
        ls[j] += v * ww;
      }
    }
    #pragma unroll
    for (int m = 1; m <= 8; m <<= 1) {
      #pragma unroll
      for (int j = 0; j < 4; j++) ls[j] += __shfl_xor(ls[j], m);
    }
    __syncthreads();
    if (p == 0) {
      #pragma unroll
      for (int j = 0; j < 4; j++) redS[rh][cs][q * 4 + j] = ls[j];
    }
    __syncthreads();
    if (t < 32) {
      int r2 = t >> 4, ri = t & 15;
      float dv = fmaxf(redS[r2][0][ri] + redS[r2][1][ri] +
                       redS[r2][2][ri] + redS[r2][3][ri] + lb[0], 0.0f);
      dpo[m0 + t] = dv;
    }
  }
}

template<int STAGE>
__global__ __launch_bounds__(512)
void conv_ln_kernel(const float* __restrict__ Xf, const u16* __restrict__ Xh,
                    const u16* __restrict__ Wp,
                    const float* __restrict__ cb,  const float* __restrict__ lgm,
                    const float* __restrict__ lbt, const float* __restrict__ lw,
                    const float* __restrict__ lb,  u16* __restrict__ Hout,
                    float* __restrict__ dpo)
{
  __shared__ __align__(16) u16 As[34 * 264 + 8];
  __shared__ __align__(16) u16 Bs[2 * 8192];
  __shared__ float sBias[256], sG[256], sB[256], sLw[256];
  __shared__ float redS[2][4][16], redQ[2][4][16];
  conv_body<STAGE>((int)blockIdx.x, (int)threadIdx.x, Xf, Xh, Wp, cb, lgm, lbt,
                   lw, lb, Hout, dpo, As, Bs, sBias, sG, sB, sLw, redS, redQ);
}

__global__ __launch_bounds__(256)
void lr_kernel(const float* __restrict__ X, const int* __restrict__ tgt,
               float* __restrict__ out) {
  __shared__ int c[L_S];
  __shared__ int sidx[TBLK];
  const int t  = threadIdx.x;
  const int n  = blockIdx.x >> 5;
  const int t0 = (blockIdx.x & 31) * TBLK;

  c[t]       = tgt[n * L_S + t];
  c[t + 256] = tgt[n * L_S + t + 256];
  __syncthreads();
  for (int off = 1; off < L_S; off <<= 1) {
    int v0 = (t >= off) ? c[t - off] : 0;
    int i1 = t + 256;
    int v1 = (i1 >= off) ? c[i1 - off] : 0;
    __syncthreads();
    c[t]  += v0;
    c[i1] += v1;
    __syncthreads();
  }
  const int total = c[L_S - 1];
  if (t < TBLK) {
    int tt = t0 + t;
    int lo = 0, hi = L_S;
    while (lo < hi) {
      int mid = (lo + hi) >> 1;
      if (c[mid] <= tt) lo = mid + 1; else hi = mid;
    }
    sidx[t] = (tt < total) ? lo : -1;
  }
  __syncthreads();

  #pragma unroll
  for (int i = 0; i < 32; i++) {
    int u   = t + i * 256;
    int dg  = u & 63;
    int tr  = u >> 6;
    int idx = sidx[tr];
    float4 v = make_float4(0.f, 0.f, 0.f, 0.f);
    if (idx >= 0)
      v = *(const float4*)(X + (((size_t)(n * L_S + idx)) << 8) + dg * 4);
    *(float4*)(out + (((size_t)(n * T_MEL + t0 + tr)) << 8) + dg * 4) = v;
  }
}

// ---------------------------------------------------------------------------
extern "C" void kernel_launch(void* const* d_in, const int* in_sizes, int n_in,
                              void* d_out, int out_size, void* d_ws, size_t ws_size,
                              hipStream_t stream) {
  (void)in_sizes; (void)n_in; (void)out_size;

  const float* x   = (const float*)d_in[0];
  const float* w1  = (const float*)d_in[1];
  const float* b1  = (const float*)d_in[2];
  const float* g1  = (const float*)d_in[3];
  const float* be1 = (const float*)d_in[4];
  const float* w2  = (const float*)d_in[5];
  const float* b2  = (const float*)d_in[6];
  const float* g2  = (const float*)d_in[7];
  const float* be2 = (const float*)d_in[8];
  const float* lw  = (const float*)d_in[9];
  const float* lb  = (const float*)d_in[10];
  const int*   tgt = (const int*)d_in[11];

  float* out = (float*)d_out;
  float* dpo = out + OUT_ELEMS;

  const size_t need = (H1_ELEMS + 2 * (size_t)WP_ELEMS) * sizeof(u16); // ~5 MB

  if (d_ws != nullptr && ws_size >= need) {
    // GLL staging; lr overlaps conv1 in one dispatch.
    u16* h1  = (u16*)d_ws;
    u16* wp1 = h1 + H1_ELEMS;
    u16* wp2 = wp1 + WP_ELEMS;
    pack_kernel<<<768, 256, 0, stream>>>(w1, w2, wp1, wp2);
    conv1_lr_gll_kernel<<<512, 512, 0, stream>>>(x, wp1, b1, g1, be1, h1, tgt, out);
    conv_gll_kernel<2><<<M_TOT / 32, 512, 0, stream>>>(
        nullptr, h1, wp2, b2, g2, be2, lw, lb, nullptr, dpo);
  } else {
    // Fallback = exact R8 (proven 121.2us): scratch in out, lr LAST.
    u16* h1  = (u16*)d_out;
    u16* wp1 = h1 + H1_ELEMS;
    u16* wp2 = wp1 + WP_ELEMS;
    pack_kernel<<<768, 256, 0, stream>>>(w1, w2, wp1, wp2);
    conv_ln_kernel<1><<<M_TOT / 32, 512, 0, stream>>>(
        x, nullptr, wp1, b1, g1, be1, nullptr, nullptr, h1, nullptr);
    conv_ln_kernel<2><<<M_TOT / 32, 512, 0, stream>>>(
        nullptr, h1, wp2, b2, g2, be2, lw, lb, nullptr, dpo);
    lr_kernel<<<N_B * (T_MEL / TBLK), 256, 0, stream>>>(x, tgt, out);
  }
}

// Round 15
// 120.898 us; speedup vs baseline: 1.1029x; 1.0740x over previous
//
#include <hip/hip_runtime.h>
#include <hip/hip_bf16.h>

using u16 = unsigned short;
typedef __bf16 bf16x8 __attribute__((ext_vector_type(8)));
typedef float f32x4 __attribute__((ext_vector_type(4)));

#define N_B   16
#define L_S   512
#define D_F   256
#define T_MEL 4096
#define M_TOT (N_B * L_S)
#define OUT_ELEMS ((size_t)N_B * T_MEL * D_F)   // fp32 elems
#define H1_ELEMS  ((size_t)M_TOT * D_F)         // bf16 elems
#define WP_ELEMS  (24 * 8192)                   // packed weight elems per conv
#define TBLK 128

__device__ __forceinline__ u16 f2bf(float f) {
  __hip_bfloat16 h = __float2bfloat16(f);
  return *(u16*)&h;
}

__device__ __forceinline__ bf16x8 pack8(float4 v0, float4 v1) {
  union { bf16x8 h; u16 u[8]; } r;
  r.u[0] = f2bf(v0.x); r.u[1] = f2bf(v0.y); r.u[2] = f2bf(v0.z); r.u[3] = f2bf(v0.w);
  r.u[4] = f2bf(v1.x); r.u[5] = f2bf(v1.y); r.u[6] = f2bf(v1.z); r.u[7] = f2bf(v1.w);
  return r.h;
}

// ---------------------------------------------------------------------------
// Weight pack: wp[s][f][ki] = w[f][(s&7)*32+ki][s>>3]  (proven indexing).
// ---------------------------------------------------------------------------
__global__ __launch_bounds__(256)
void pack_kernel(const float* __restrict__ w1, const float* __restrict__ w2,
                 u16* __restrict__ wp1, u16* __restrict__ wp2) {
  int o   = (int)blockIdx.x * 256 + (int)threadIdx.x;   // 0..196607
  int s   = o >> 13;
  int rem = o & 8191;
  int f   = rem >> 5;
  int ki  = rem & 31;
  int d   = ((s & 7) << 5) + ki;
  int tap = s >> 3;
  int src = f * 768 + d * 3 + tap;
  wp1[o] = f2bf(w1[src]);
  wp2[o] = f2bf(w2[src]);
}

// ---------------------------------------------------------------------------
// Conv body — R8 VERBATIM (proven 121.2us / absmax 0.003418), the empirical
// optimum after the full falsification matrix (R4 occupancy/chain null,
// R9 depth-3 spill, R11 vmcnt-drain null, R12 fusion worse, R13 no-LDS
// worse, R14 global_load_lds worse). 32-row x 256-col tile, A staged once
// in LDS (stride 264), B double-buffered through LDS, loads 2 steps ahead
// via named even/odd reg pairs (no pragma unroll), one barrier per step.
// 8 waves = 2 row-halves x 4 col-slices, proven epilogue.
// ---------------------------------------------------------------------------
template<int STAGE>
__device__ __forceinline__ void conv_body(
    const int blk, const int t,
    const float* __restrict__ Xf, const u16* __restrict__ Xh,
    const u16* __restrict__ Wp,
    const float* __restrict__ cb,  const float* __restrict__ lgm,
    const float* __restrict__ lbt, const float* __restrict__ lw,
    const float* __restrict__ lb,  u16* __restrict__ Hout,
    float* __restrict__ dpo,
    u16* As, u16* Bs, float* sBias, float* sG, float* sB, float* sLw,
    float (*redS)[4][16], float (*redQ)[4][16])
{
  if (t < 256) {
    sBias[t] = cb[t];
    sG[t]    = lgm[t];
    sB[t]    = lbt[t];
    if (STAGE == 2) sLw[t] = lw[t];
  }

  const int m0   = blk * 32;
  const int n    = m0 >> 9;
  const int l0   = m0 & 511;
  const int wave = t >> 6, lane = t & 63;
  const int cs   = wave & 3;
  const int rh   = wave >> 2;
  const int wc   = cs * 64;
  const int rh16 = rh * 16;
  const int p    = lane & 15, q = lane >> 4;

  f32x4 acc[4];
  #pragma unroll
  for (int i = 0; i < 4; i++) acc[i] = (f32x4){0.f, 0.f, 0.f, 0.f};

  auto LDW = [&](int s, uint4 &r0, uint4 &r1) {
    const u16* src = Wp + ((size_t)s << 13);
    r0 = *(const uint4*)(src + (t << 3));
    r1 = *(const uint4*)(src + ((t + 512) << 3));
  };
  auto WRB = [&](int buf, const uint4 &r0, const uint4 &r1) {
    *(uint4*)(Bs + (buf << 13) + (t << 3))         = r0;
    *(uint4*)(Bs + (buf << 13) + ((t + 512) << 3)) = r1;
  };
  auto MF = [&](int buf, int s) {
    const u16* bs = Bs + (buf << 13);
    const int tap = s >> 3, dbase = (s & 7) << 5;
    bf16x8 af = *(const bf16x8*)(As + (rh16 + p + tap) * 264 + dbase + (q << 3));
    #pragma unroll
    for (int ct = 0; ct < 4; ct++) {
      bf16x8 bfr = *(const bf16x8*)(bs + ((wc + ct * 16 + p) << 5) + (q << 3));
      acc[ct] = __builtin_amdgcn_mfma_f32_16x16x32_bf16(af, bfr, acc[ct], 0, 0, 0);
    }
  };

  // ---- prologue: issue L(0), L(1); stage A; publish buf0 ----
  uint4 e0, e1, o0, o1;                   // even / odd pipeline reg pairs
  LDW(0, e0, e1);
  LDW(1, o0, o1);

  for (int c = t; c < 1088; c += 512) {   // stage A once (34 x 256, bf16)
    int row  = c >> 5;
    int col8 = c & 31;
    int l    = l0 + row - 1;
    uint4 val;
    if ((unsigned)l < 512u) {
      if (STAGE == 1) {
        const float* src = Xf + (((size_t)((n << 9) + l)) << 8) + (col8 << 3);
        float4 v0 = *(const float4*)src;
        float4 v1 = *(const float4*)(src + 4);
        bf16x8 pk = pack8(v0, v1);
        __builtin_memcpy(&val, &pk, 16);
      } else {
        val = *(const uint4*)(Xh + (((size_t)((n << 9) + l)) << 8) + (col8 << 3));
      }
    } else {
      val = make_uint4(0u, 0u, 0u, 0u);
    }
    *(uint4*)(As + row * 264 + (col8 << 3)) = val;
  }
  WRB(0, e0, e1);
  __syncthreads();

  // ---- K-loop: one barrier per step, loads 2 ahead (R8 schedule) ----
  for (int s2 = 0; s2 < 24; s2 += 2) {
    // even step s2: read buf0
    MF(0, s2);
    if (s2 + 2 < 24) LDW(s2 + 2, e0, e1);
    WRB(1, o0, o1);                       // publish L(s2+1) for next step
    __syncthreads();
    // odd step s2+1: read buf1
    MF(1, s2 + 1);
    if (s2 + 3 < 24) LDW(s2 + 3, o0, o1);
    if (s2 + 2 < 24) WRB(0, e0, e1);      // publish L(s2+2)
    __syncthreads();
  }

  // ---- bias + per-row sum / sumsq over this wave's 64 cols (proven) ----
  float s0[4] = {0,0,0,0}, s1[4] = {0,0,0,0};
  #pragma unroll
  for (int ct = 0; ct < 4; ct++) {
    float bias = sBias[wc + ct * 16 + p];
    #pragma unroll
    for (int j = 0; j < 4; j++) {
      float v = acc[ct][j] + bias;
      acc[ct][j] = v;
      s0[j] += v;
      s1[j] += v * v;
    }
  }
  #pragma unroll
  for (int m = 1; m <= 8; m <<= 1) {
    #pragma unroll
    for (int j = 0; j < 4; j++) {
      s0[j] += __shfl_xor(s0[j], m);
      s1[j] += __shfl_xor(s1[j], m);
    }
  }
  if (p == 0) {
    #pragma unroll
    for (int j = 0; j < 4; j++) {
      redS[rh][cs][q * 4 + j] = s0[j];
      redQ[rh][cs][q * 4 + j] = s1[j];
    }
  }
  __syncthreads();
  float mean[4], rstd[4];
  #pragma unroll
  for (int j = 0; j < 4; j++) {
    int r = q * 4 + j;
    float S = redS[rh][0][r] + redS[rh][1][r] + redS[rh][2][r] + redS[rh][3][r];
    float Q = redQ[rh][0][r] + redQ[rh][1][r] + redQ[rh][2][r] + redQ[rh][3][r];
    float mu  = S * (1.0f / 256.0f);
    float var = Q * (1.0f / 256.0f) - mu * mu;
    mean[j] = mu;
    rstd[j] = rsqrtf(var + 1e-5f);
  }

  if (STAGE == 1) {
    #pragma unroll
    for (int ct = 0; ct < 4; ct++) {
      int c = wc + ct * 16 + p;
      float gg = sG[c], bb = sB[c];
      #pragma unroll
      for (int j = 0; j < 4; j++) {
        float v = (acc[ct][j] - mean[j]) * rstd[j] * gg + bb;
        v = fmaxf(v, 0.0f);
        Hout[(size_t)(m0 + rh16 + q * 4 + j) * 256 + c] = f2bf(v);
      }
    }
  } else {
    float ls[4] = {0,0,0,0};
    #pragma unroll
    for (int ct = 0; ct < 4; ct++) {
      int c = wc + ct * 16 + p;
      float gg = sG[c], bb = sB[c], ww = sLw[c];
      #pragma unroll
      for (int j = 0; j < 4; j++) {
        float v = (acc[ct][j] - mean[j]) * rstd[j] * gg + bb;
        v = fmaxf(v, 0.0f);
        ls[j] += v * ww;
      }
    }
    #pragma unroll
    for (int m = 1; m <= 8; m <<= 1) {
      #pragma unroll
      for (int j = 0; j < 4; j++) ls[j] += __shfl_xor(ls[j], m);
    }
    __syncthreads();
    if (p == 0) {
      #pragma unroll
      for (int j = 0; j < 4; j++) redS[rh][cs][q * 4 + j] = ls[j];
    }
    __syncthreads();
    if (t < 32) {
      int r2 = t >> 4, ri = t & 15;
      float dv = fmaxf(redS[r2][0][ri] + redS[r2][1][ri] +
                       redS[r2][2][ri] + redS[r2][3][ri] + lb[0], 0.0f);
      dpo[m0 + t] = dv;
    }
  }
}

// ---------------------------------------------------------------------------
// 512-thread LR body (proven in R6/R7): 256 lr-blocks, 256 T-rows each.
// ---------------------------------------------------------------------------
__device__ __forceinline__ void lr_body512(
    const int lrblk, const int t,
    const float* __restrict__ X, const int* __restrict__ tgt,
    float* __restrict__ out, int* sc, int* sidx)
{
  const int n  = lrblk >> 4;                    // 16 super-chunks per n
  const int t0 = (lrblk & 15) * 256;

  sc[t] = tgt[n * L_S + t];
  __syncthreads();
  for (int off = 1; off < L_S; off <<= 1) {
    int v = (t >= off) ? sc[t - off] : 0;
    __syncthreads();
    sc[t] += v;
    __syncthreads();
  }
  const int total = sc[L_S - 1];
  if (t < 256) {
    int tt = t0 + t;
    int lo = 0, hi = L_S;
    while (lo < hi) {                           // upper_bound: first sc[i] > tt
      int mid = (lo + hi) >> 1;
      if (sc[mid] <= tt) lo = mid + 1; else hi = mid;
    }
    sidx[t] = (tt < total) ? lo : -1;
  }
  __syncthreads();

  #pragma unroll
  for (int i = 0; i < 32; i++) {
    int u   = t + i * 512;                      // 256 rows x 64 float4
    int dg  = u & 63;
    int tr  = u >> 6;
    int idx = sidx[tr];
    float4 v = make_float4(0.f, 0.f, 0.f, 0.f);
    if (idx >= 0)
      v = *(const float4*)(X + (((size_t)(n * L_S + idx)) << 8) + dg * 4);
    *(float4*)(out + (((size_t)(n * T_MEL + t0 + tr)) << 8) + dg * 4) = v;
  }
}

// ---------------------------------------------------------------------------
// Standalone kernels.
// ---------------------------------------------------------------------------
template<int STAGE>
__global__ __launch_bounds__(512)
void conv_ln_kernel(const float* __restrict__ Xf, const u16* __restrict__ Xh,
                    const u16* __restrict__ Wp,
                    const float* __restrict__ cb,  const float* __restrict__ lgm,
                    const float* __restrict__ lbt, const float* __restrict__ lw,
                    const float* __restrict__ lb,  u16* __restrict__ Hout,
                    float* __restrict__ dpo)
{
  __shared__ __align__(16) u16 As[34 * 264 + 8];
  __shared__ __align__(16) u16 Bs[2 * 8192];
  __shared__ float sBias[256], sG[256], sB[256], sLw[256];
  __shared__ float redS[2][4][16], redQ[2][4][16];
  conv_body<STAGE>((int)blockIdx.x, (int)threadIdx.x, Xf, Xh, Wp, cb, lgm, lbt,
                   lw, lb, Hout, dpo, As, Bs, sBias, sG, sB, sLw, redS, redQ);
}

// Fused: blocks 0..255 = conv stage 1; blocks 256..511 = length-regulate.
// Valid ONLY on the d_ws path (scratch outside the out region).
__global__ __launch_bounds__(512)
void conv1_lr_kernel(const float* __restrict__ x, const u16* __restrict__ Wp,
                     const float* __restrict__ cb,  const float* __restrict__ lgm,
                     const float* __restrict__ lbt, u16* __restrict__ Hout,
                     const int* __restrict__ tgt, float* __restrict__ out)
{
  __shared__ __align__(16) u16 As[34 * 264 + 8];
  __shared__ __align__(16) u16 Bs[2 * 8192];
  __shared__ float sBias[256], sG[256], sB[256], sLw[256];
  __shared__ float redS[2][4][16], redQ[2][4][16];
  __shared__ int  sc[512];
  __shared__ int  sidx[256];

  const int blk = (int)blockIdx.x, t = (int)threadIdx.x;
  if (blk < 256) {
    conv_body<1>(blk, t, x, nullptr, Wp, cb, lgm, lbt, nullptr, nullptr,
                 Hout, nullptr, As, Bs, sBias, sG, sB, sLw, redS, redQ);
  } else {
    lr_body512(blk - 256, t, x, tgt, out, sc, sidx);
  }
}

// Fallback LR (proven): 512 blocks x 256 thr, runs LAST.
__global__ __launch_bounds__(256)
void lr_kernel(const float* __restrict__ X, const int* __restrict__ tgt,
               float* __restrict__ out) {
  __shared__ int c[L_S];
  __shared__ int sidx[TBLK];
  const int t  = threadIdx.x;
  const int n  = blockIdx.x >> 5;
  const int t0 = (blockIdx.x & 31) * TBLK;

  c[t]       = tgt[n * L_S + t];
  c[t + 256] = tgt[n * L_S + t + 256];
  __syncthreads();
  for (int off = 1; off < L_S; off <<= 1) {
    int v0 = (t >= off) ? c[t - off] : 0;
    int i1 = t + 256;
    int v1 = (i1 >= off) ? c[i1 - off] : 0;
    __syncthreads();
    c[t]  += v0;
    c[i1] += v1;
    __syncthreads();
  }
  const int total = c[L_S - 1];
  if (t < TBLK) {
    int tt = t0 + t;
    int lo = 0, hi = L_S;
    while (lo < hi) {
      int mid = (lo + hi) >> 1;
      if (c[mid] <= tt) lo = mid + 1; else hi = mid;
    }
    sidx[t] = (tt < total) ? lo : -1;
  }
  __syncthreads();

  #pragma unroll
  for (int i = 0; i < 32; i++) {
    int u   = t + i * 256;
    int dg  = u & 63;
    int tr  = u >> 6;
    int idx = sidx[tr];
    float4 v = make_float4(0.f, 0.f, 0.f, 0.f);
    if (idx >= 0)
      v = *(const float4*)(X + (((size_t)(n * L_S + idx)) << 8) + dg * 4);
    *(float4*)(out + (((size_t)(n * T_MEL + t0 + tr)) << 8) + dg * 4) = v;
  }
}

// ---------------------------------------------------------------------------
extern "C" void kernel_launch(void* const* d_in, const int* in_sizes, int n_in,
                              void* d_out, int out_size, void* d_ws, size_t ws_size,
                              hipStream_t stream) {
  (void)in_sizes; (void)n_in; (void)out_size;

  const float* x   = (const float*)d_in[0];
  const float* w1  = (const float*)d_in[1];
  const float* b1  = (const float*)d_in[2];
  const float* g1  = (const float*)d_in[3];
  const float* be1 = (const float*)d_in[4];
  const float* w2  = (const float*)d_in[5];
  const float* b2  = (const float*)d_in[6];
  const float* g2  = (const float*)d_in[7];
  const float* be2 = (const float*)d_in[8];
  const float* lw  = (const float*)d_in[9];
  const float* lb  = (const float*)d_in[10];
  const int*   tgt = (const int*)d_in[11];

  float* out = (float*)d_out;
  float* dpo = out + OUT_ELEMS;

  const size_t need = (H1_ELEMS + 2 * (size_t)WP_ELEMS) * sizeof(u16); // ~5 MB

  if (d_ws != nullptr && ws_size >= need) {
    // Scratch OUTSIDE the out region -> lr overlaps conv1 in one dispatch.
    u16* h1  = (u16*)d_ws;
    u16* wp1 = h1 + H1_ELEMS;
    u16* wp2 = wp1 + WP_ELEMS;
    pack_kernel<<<768, 256, 0, stream>>>(w1, w2, wp1, wp2);
    conv1_lr_kernel<<<512, 512, 0, stream>>>(x, wp1, b1, g1, be1, h1, tgt, out);
    conv_ln_kernel<2><<<M_TOT / 32, 512, 0, stream>>>(
        nullptr, h1, wp2, b2, g2, be2, lw, lb, nullptr, dpo);
  } else {
    // Fallback: scratch in out, lr LAST.
    u16* h1  = (u16*)d_out;
    u16* wp1 = h1 + H1_ELEMS;
    u16* wp2 = wp1 + WP_ELEMS;
    pack_kernel<<<768, 256, 0, stream>>>(w1, w2, wp1, wp2);
    conv_ln_kernel<1><<<M_TOT / 32, 512, 0, stream>>>(
        x, nullptr, wp1, b1, g1, be1, nullptr, nullptr, h1, nullptr);
    conv_ln_kernel<2><<<M_TOT / 32, 512, 0, stream>>>(
        nullptr, h1, wp2, b2, g2, be2, lw, lb, nullptr, dpo);
    lr_kernel<<<N_B * (T_MEL / TBLK), 256, 0, stream>>>(x, tgt, out);
  }
}